// Round 9
// baseline (3781.758 us; speedup 1.0000x reference)
//
#include <hip/hip_runtime.h>
#include <stdint.h>

#define NB 16
#define NS 256
#define NV 32000
#define NE 512
#define NH 1024
#define PAD_IDX 3

// workspace byte offsets
#define WS_XP    0L                 // f32 [4096][1024]   16,777,216 B
#define WS_HCH   16777216L          // bf16 mirror [257][16][1024] 8,421,376 B
#define WS_WHO   25198592L          // bf16 [32000][1024] 65,536,000 B
#define WS_LOC   90734592L          // bf16 local [2][16][1024]  65,536 B
#define WS_FL    90800128L          // u8 fl_loc[257][256]       65,792 B
#define WS_F3    90865920L          // u8 flg3 [257][256]        65,792 B
#define WS_REF   90931712L          // u32 xcd ref                    4 B
#define WS_NEED  90931716L

typedef __attribute__((ext_vector_type(8))) short bf16x8;
typedef __attribute__((ext_vector_type(4))) float f32x4;
typedef __attribute__((ext_vector_type(4))) uint32_t u32x4;

__device__ __forceinline__ uint16_t f2bf(float f){
  union { float f; uint32_t u; } v; v.f = f;
  return (uint16_t)((v.u + 0x7fffu + ((v.u >> 16) & 1u)) >> 16);  // RNE
}

__device__ __forceinline__ bf16x8 pack8(float4 a, float4 b){
  bf16x8 r;
  r[0]=(short)f2bf(a.x); r[1]=(short)f2bf(a.y); r[2]=(short)f2bf(a.z); r[3]=(short)f2bf(a.w);
  r[4]=(short)f2bf(b.x); r[5]=(short)f2bf(b.y); r[6]=(short)f2bf(b.z); r[7]=(short)f2bf(b.w);
  return r;
}

// ---- L3-scope (device-coherent) ops: bypass L1+L2
__device__ __forceinline__ u32x4 load_coh16(const void* p){
  u32x4 r;
  asm volatile("global_load_dwordx4 %0, %1, off sc0 sc1" : "=v"(r) : "v"(p) : "memory");
  return r;
}
__device__ __forceinline__ uint32_t load_coh4(const void* p){
  uint32_t r;
  asm volatile("global_load_dword %0, %1, off sc0 sc1" : "=v"(r) : "v"(p) : "memory");
  return r;
}
__device__ __forceinline__ uint32_t load_u8_coh(const void* p){
  uint32_t r;
  asm volatile("global_load_ubyte %0, %1, off sc0 sc1" : "=v"(r) : "v"(p) : "memory");
  return r;
}
__device__ __forceinline__ void store_coh4(void* p, uint32_t v){
  asm volatile("global_store_dword %0, %1, off sc0 sc1" :: "v"(p), "v"(v) : "memory");
}
__device__ __forceinline__ void store_u8_coh(void* p, uint32_t v){
  asm volatile("global_store_byte %0, %1, off sc0 sc1" :: "v"(p), "v"(v) : "memory");
}
// ---- L2-scope ops: bypass L1 only (coherent within one XCD's shared L2)
__device__ __forceinline__ u32x4 load_l2_16(const void* p){
  u32x4 r;
  asm volatile("global_load_dwordx4 %0, %1, off sc0" : "=v"(r) : "v"(p) : "memory");
  return r;
}
__device__ __forceinline__ uint32_t load_u8_l2(const void* p){
  uint32_t r;
  asm volatile("global_load_ubyte %0, %1, off sc0" : "=v"(r) : "v"(p) : "memory");
  return r;
}
__device__ __forceinline__ void store_l2_4(void* p, uint32_t v){
  asm volatile("global_store_dword %0, %1, off sc0" :: "v"(p), "v"(v) : "memory");
}
__device__ __forceinline__ void store_u8_l2(void* p, uint32_t v){
  asm volatile("global_store_byte %0, %1, off sc0" :: "v"(p), "v"(v) : "memory");
}

// clamped fast tanh: (e^{2x}-1)/(e^{2x}+1) via exp2; abs err ~1e-5, never NaN/inf
__device__ __forceinline__ float tanh_fast(float x){
  x = fminf(fmaxf(x, -10.f), 10.f);
  float t = __builtin_amdgcn_exp2f(x * 2.885390081777927f);  // 2*log2(e)
  return (t - 1.0f) * __builtin_amdgcn_rcpf(t + 1.0f);
}

// ---- K0: zero both flag arrays (step0 = 1), h0 -> mirror slot 0 + local slot 0
__global__ void k_init(const float* __restrict__ hidden, uint16_t* __restrict__ hmir,
                       uint16_t* __restrict__ hloc, uint32_t* __restrict__ fl32,
                       uint32_t* __restrict__ f332, uint32_t* __restrict__ xref){
  int idx = blockIdx.x * 256 + threadIdx.x;   // 128*256 = 32768
  if (idx < 16448){
    uint32_t v = (idx < 64) ? 0x01010101u : 0u;   // first 256 bytes = step 0 done
    fl32[idx] = v;
    f332[idx] = v;
  }
  if (idx < NB * NH){
    uint16_t v = f2bf(hidden[idx]);
    hmir[idx] = v;
    hloc[idx] = v;
  }
  if (idx == 0) *xref = ~0u;
}

// ---- K1: Who_w f32 -> bf16 (row-major [32000][1024])
__global__ void k_cvt(const float* __restrict__ src, uint32_t* __restrict__ dst){
  long idx = (long)blockIdx.x * 256 + threadIdx.x;  // 4,096,000 threads, 8 f32 each
  const float4* p = (const float4*)src;
  float4 a = p[idx*2], b = p[idx*2+1];
  u32x4 d;
  d[0] = (uint32_t)f2bf(a.x) | ((uint32_t)f2bf(a.y) << 16);
  d[1] = (uint32_t)f2bf(a.z) | ((uint32_t)f2bf(a.w) << 16);
  d[2] = (uint32_t)f2bf(b.x) | ((uint32_t)f2bf(b.y) << 16);
  d[3] = (uint32_t)f2bf(b.z) | ((uint32_t)f2bf(b.w) << 16);
  ((u32x4*)dst)[idx] = d;
}

// ---- K2: xp[m][n] = sum_k emb(ids[m])[k] * Wxh[n][k] + b[n]   (m=(b,s), bf16 MFMA)
__global__ __launch_bounds__(256) void k_xproj(
    const int* __restrict__ ids, const float* __restrict__ tab,
    const float* __restrict__ wxh, const float* __restrict__ bxh,
    float* __restrict__ xp){
  int bid = blockIdx.x;                 // 64 M-tiles x 16 N-tiles
  int tm = bid & 63, tn = bid >> 6;
  int Mb = tm * 64, Nb = tn * 64;
  int tid = threadIdx.x;
  int w = tid >> 6, l = tid & 63;
  int lr = l & 15, lk = l >> 4;

  int m = Mb + w*16 + lr;
  int id = ids[m];
  const float* arow = tab + (long)id * NE;
  bool pad = (id == PAD_IDX);

  f32x4 acc[4];
  #pragma unroll
  for (int j = 0; j < 4; ++j) acc[j] = (f32x4){0.f,0.f,0.f,0.f};

  for (int k0 = 0; k0 < NE; k0 += 32){
    int k = k0 + lk*8;
    bf16x8 af = (bf16x8){0,0,0,0,0,0,0,0};
    if (!pad){
      float4 a = *(const float4*)(arow + k);
      float4 b = *(const float4*)(arow + k + 4);
      af = pack8(a, b);
    }
    #pragma unroll
    for (int j = 0; j < 4; ++j){
      const float* brow = wxh + (long)(Nb + j*16 + lr) * NE + k;
      float4 x = *(const float4*)brow;
      float4 y = *(const float4*)(brow + 4);
      bf16x8 bf_ = pack8(x, y);
      acc[j] = __builtin_amdgcn_mfma_f32_16x16x32_bf16(af, bf_, acc[j], 0, 0, 0);
    }
  }
  #pragma unroll
  for (int j = 0; j < 4; ++j){
    int n = Nb + j*16 + lr;
    float bias = bxh[n];
    #pragma unroll
    for (int r = 0; r < 4; ++r){
      int row = Mb + w*16 + lk*4 + r;
      xp[(long)row * NH + n] = acc[j][r] + bias;
    }
  }
}

// ---- K3 fused.
// RNN (bids {0,8,...,504} -> XCD0 under bid%8 model): 4 groups x 16 blocks x
//   4 waves; group g owns batches 4g..4g+3; wave owns 16 cols, Whh in 128 regs.
//   Two-level handshake: FAST = sc0 byte-flags + 2-slot local h (XCD0 L2
//   coherence; causally safe slot reuse); FALLBACK (every 4th poll, or when
//   XCC_ID mismatch) = sc0sc1 flg3 flags + full-size L3 mirror. flg3[t][wave]
//   set after the wave's slot-t mirror stores drain (first poll vmcnt of step
//   t) -> GEMM gate ground truth. No sentinels anywhere.
// GEMM (8000 tiles): reg-staged 128x128, s-major M (tile tm spans 8 steps),
//   A from mirror, gated on flg3[tm*8+8][0..255].
__global__ __launch_bounds__(256, 2) void k_fused(
    const float* __restrict__ whh, const float* __restrict__ xp,
    uint16_t* __restrict__ hch, uint16_t* __restrict__ hloc,
    const uint16_t* __restrict__ whobf, const float* __restrict__ whob,
    uint8_t* __restrict__ fl_loc, uint8_t* __restrict__ flg3,
    uint32_t* __restrict__ xcdref, float* __restrict__ out,
    float* __restrict__ hfin){
  __shared__ __align__(16) char smem[16*1024 + 1024];
  const int bid = blockIdx.x;
  const int tid = threadIdx.x;

  if (bid < 512 && (bid & 7) == 0){
    // ================= RNN path =================
    const int role = bid >> 3;          // 0..63
    const int g = role >> 4, c = role & 15;
    const int j = tid >> 6, l = tid & 63;
    const int lr = l & 15, lk = l >> 4;
    const int ncol = c*64 + j*16 + lr;
    const int wsel = g*64 + c*4 + j;
    __builtin_amdgcn_s_setprio(2);

    uint32_t myx = (uint32_t)__builtin_amdgcn_s_getreg(63508) ^ 0x5A5A0000u; // HW_REG_XCC_ID
    if (role == 0 && j == 0 && l == 0) store_coh4(xcdref, myx);

    // Whh slice -> registers: row ncol, all K (32 x bf16x8)
    bf16x8 wf[32];
    #pragma unroll
    for (int kk = 0; kk < 32; ++kk){
      const float* s0 = whh + (long)ncol * NH + kk*32 + lk*8;
      wf[kk] = pack8(*(const float4*)s0, *(const float4*)(s0 + 4));
    }

    float xpreg[4];
    if (l < 16){
      #pragma unroll
      for (int r = 0; r < 4; ++r)
        xpreg[r] = xp[((long)(4*g + r) * NS + 0) * NH + ncol];
    }

    uint32_t refx;
    while (true){
      refx = load_coh4(xcdref);
      asm volatile("s_waitcnt vmcnt(0)" ::: "memory");
      __builtin_amdgcn_sched_barrier(0);
      if (refx != ~0u) break;
    }
    const bool allowLocal = (refx == myx);

    for (int t = 0; t < NS; ++t){
      // ---- poll flags for slot t
      const uint8_t* fpl = fl_loc + t*256 + g*64 + l;
      const uint8_t* fp3 = flg3  + t*256 + g*64 + l;
      bool first = true, useMir = false;
      int it = 0;
      while (true){
        bool slow = (!allowLocal) || ((it & 3) == 3);
        uint32_t b = slow ? load_u8_coh(fp3) : load_u8_l2(fpl);
        asm volatile("s_waitcnt vmcnt(0)" ::: "memory");
        __builtin_amdgcn_sched_barrier(0);   // pin check AFTER waitcnt (rule #18)
        if (first){
          // our slot-t mirror stores (issued at step t-1) just drained
          if (l == 0 && t > 0) store_u8_coh(flg3 + t*256 + wsel, 1u);
          first = false;
        }
        if (__all(b != 0u)){ useMir = slow; break; }
        ++it;
      }
      __builtin_amdgcn_sched_barrier(0);

      const char* srcM = (const char*)hch  + (((long)t       * NB + 4*g + (lr & 3)) * NH) * 2 + lk * 16;
      const char* srcL = (const char*)hloc + (((long)(t & 1) * NB + 4*g + (lr & 3)) * NH) * 2 + lk * 16;

      f32x4 acc = (f32x4){0.f,0.f,0.f,0.f};
      #pragma unroll
      for (int half = 0; half < 2; ++half){
        u32x4 ha[16];
        if (useMir){
          if (lr < 4){
            #pragma unroll
            for (int q = 0; q < 16; ++q) ha[q] = load_coh16(srcM + (half*16 + q)*64);
          }
        } else {
          if (lr < 4){
            #pragma unroll
            for (int q = 0; q < 16; ++q) ha[q] = load_l2_16(srcL + (half*16 + q)*64);
          }
        }
        asm volatile("s_waitcnt vmcnt(0)" ::: "memory");
        __builtin_amdgcn_sched_barrier(0);
        #pragma unroll
        for (int q = 0; q < 16; ++q)
          acc = __builtin_amdgcn_mfma_f32_16x16x32_bf16(
                  *(const bf16x8*)&ha[q], wf[half*16 + q], acc, 0, 0, 0);
      }

      // epilogue: lanes 0..15 hold batches 4g..4g+3 for col ncol
      uint32_t wpk[4];
      if (l < 16){
        #pragma unroll
        for (int r = 0; r < 4; ++r){
          float hv = tanh_fast(xpreg[r] + acc[r]);
          if (t == NS-1) hfin[(long)(4*g + r) * NH + ncol] = hv;
          uint32_t hb = (uint32_t)f2bf(hv);
          uint32_t ob = (uint32_t)__shfl_xor((int)hb, 1);
          wpk[r] = hb | (ob << 16);        // cols (ncol, ncol+1) packed, even lanes
        }
      }
      // local stores -> fast L2 ack -> local flag
      if (l < 16 && (l & 1) == 0){
        #pragma unroll
        for (int r = 0; r < 4; ++r){
          char* dl = (char*)hloc + (((long)((t+1) & 1) * NB + 4*g + r) * NH + ncol) * 2;
          store_l2_4(dl, wpk[r]);
        }
      }
      asm volatile("s_waitcnt vmcnt(0)" ::: "memory");
      __builtin_amdgcn_sched_barrier(0);
      if (l == 0) store_u8_l2(fl_loc + (t+1)*256 + wsel, 1u);
      // mirror stores (fire-and-forget; acked by next step's first poll vmcnt)
      if (l < 16 && (l & 1) == 0){
        #pragma unroll
        for (int r = 0; r < 4; ++r){
          char* dm = (char*)hch + (((long)(t+1) * NB + 4*g + r) * NH + ncol) * 2;
          store_coh4(dm, wpk[r]);
        }
      }
      if (l < 16 && t + 1 < NS){
        #pragma unroll
        for (int r = 0; r < 4; ++r)
          xpreg[r] = xp[((long)(4*g + r) * NS + (t+1)) * NH + ncol];
      }
    }
    asm volatile("s_waitcnt vmcnt(0)" ::: "memory");   // slot-256 mirror acked
    if (l == 0) store_u8_coh(flg3 + NS*256 + wsel, 1u);
    return;
  }

  // ================= logits path (reg-staged, s-major tiles) =================
  uint16_t* As = (uint16_t*)smem;          // 8 KB
  uint16_t* Bs = (uint16_t*)(smem + 8192); // 8 KB
  int tile = (bid < 512) ? (bid - ((bid + 7) >> 3)) : (bid - 64);  // 0..7999
  int tm = tile / 250;                     // s-group (8 steps per tile)
  int tn = tile % 250;
  int Mb = tm * 128, Nb = tn * 128;
  int hs = tm * 8 + 8;                     // highest needed slot

  {  // gate: 256 bytes of flg3[hs]
    const uint8_t* gp = flg3 + hs*256 + tid;
    while (true){
      uint32_t f = load_u8_coh(gp);
      asm volatile("s_waitcnt vmcnt(0)" ::: "memory");
      __builtin_amdgcn_sched_barrier(0);
      if (__syncthreads_count(f == 0u) == 0) break;
      __builtin_amdgcn_s_sleep(16);
    }
  }

  int wv = tid >> 6, l = tid & 63;
  int wm = wv >> 1, wn = wv & 1;
  int lr = l & 15, lk = l >> 4;

  int r0 = tid >> 2, c0 = tid & 3;
  int r1 = r0 + 64;
  // s-major: A row m <-> mirror row m+16 (contiguous)
  const uint16_t* pa0 = hch + (long)(Mb + r0 + 16) * NH + c0*8;
  const uint16_t* pa1 = hch + (long)(Mb + r1 + 16) * NH + c0*8;
  const uint16_t* pb0 = whobf + (long)(Nb + r0) * NH + c0*8;
  const uint16_t* pb1 = whobf + (long)(Nb + r1) * NH + c0*8;
  int da0 = r0*4 + (c0 ^ (r0 & 3));
  int da1 = r1*4 + (c0 ^ (r1 & 3));

  u32x4 ra0 = *(const u32x4*)pa0;
  u32x4 ra1 = *(const u32x4*)pa1;
  u32x4 rb0 = *(const u32x4*)pb0;
  u32x4 rb1 = *(const u32x4*)pb1;

  f32x4 acc[4][4];
  #pragma unroll
  for (int i = 0; i < 4; ++i)
    #pragma unroll
    for (int jj = 0; jj < 4; ++jj) acc[i][jj] = (f32x4){0.f,0.f,0.f,0.f};

  for (int kt = 0; kt < 32; ++kt){
    ((u32x4*)As)[da0] = ra0;
    ((u32x4*)As)[da1] = ra1;
    ((u32x4*)Bs)[da0] = rb0;
    ((u32x4*)Bs)[da1] = rb1;
    __syncthreads();
    if (kt != 31){
      int off = (kt + 1) * 32;
      ra0 = *(const u32x4*)(pa0 + off);
      ra1 = *(const u32x4*)(pa1 + off);
      rb0 = *(const u32x4*)(pb0 + off);
      rb1 = *(const u32x4*)(pb1 + off);
    }
    bf16x8 af[4], bg_[4];
    #pragma unroll
    for (int i = 0; i < 4; ++i){
      int ra = wm*64 + i*16 + lr;
      int rb = wn*64 + i*16 + lr;
      af[i]  = *(const bf16x8*)&((const u32x4*)As)[ra*4 + (lk ^ (ra & 3))];
      bg_[i] = *(const bf16x8*)&((const u32x4*)Bs)[rb*4 + (lk ^ (rb & 3))];
    }
    #pragma unroll
    for (int i = 0; i < 4; ++i)
      #pragma unroll
      for (int jj = 0; jj < 4; ++jj)
        acc[i][jj] = __builtin_amdgcn_mfma_f32_16x16x32_bf16(af[i], bg_[jj], acc[i][jj], 0, 0, 0);
    __syncthreads();
  }

  #pragma unroll
  for (int jj = 0; jj < 4; ++jj){
    int col = Nb + wn*64 + jj*16 + lr;
    float bias = whob[col];
    #pragma unroll
    for (int i = 0; i < 4; ++i){
      #pragma unroll
      for (int rr = 0; rr < 4; ++rr){
        int m = Mb + wm*64 + i*16 + lk*4 + rr;      // m = s*16 + b
        long orow = (long)((m & 15) * 256 + (m >> 4));
        out[orow * NV + col] = acc[i][jj][rr] + bias;
      }
    }
  }
}

extern "C" void kernel_launch(void* const* d_in, const int* in_sizes, int n_in,
                              void* d_out, int out_size, void* d_ws, size_t ws_size,
                              hipStream_t stream){
  (void)in_sizes; (void)n_in; (void)out_size;
  if (ws_size < (size_t)WS_NEED) return;   // insufficient scratch -> fail loudly (poison stays)

  const int*   ids    = (const int*)  d_in[0];
  const float* hidden = (const float*)d_in[1];
  const float* table  = (const float*)d_in[2];
  const float* wxh    = (const float*)d_in[3];
  const float* bxh    = (const float*)d_in[4];
  const float* whh    = (const float*)d_in[5];
  const float* who    = (const float*)d_in[6];
  const float* whob   = (const float*)d_in[7];

  char* ws = (char*)d_ws;
  float*    xp     = (float*)   (ws + WS_XP);
  uint16_t* hchain = (uint16_t*)(ws + WS_HCH);   // mirror (L3)
  uint16_t* whobf  = (uint16_t*)(ws + WS_WHO);
  uint16_t* hloc   = (uint16_t*)(ws + WS_LOC);   // 2-slot local (XCD0 L2)
  uint8_t*  fl_loc = (uint8_t*) (ws + WS_FL);
  uint8_t*  flg3   = (uint8_t*) (ws + WS_F3);
  uint32_t* xcdref = (uint32_t*)(ws + WS_REF);
  float* out    = (float*)d_out;
  float* hfinal = out + (long)NB * NS * NV;   // 131,072,000

  k_init <<<128,   256, 0, stream>>>(hidden, hchain, hloc,
                                     (uint32_t*)fl_loc, (uint32_t*)flg3, xcdref);
  k_cvt  <<<16000, 256, 0, stream>>>(who, (uint32_t*)whobf);
  k_xproj<<<1024,  256, 0, stream>>>(ids, table, wxh, bxh, xp);
  k_fused<<<8064,  256, 0, stream>>>(whh, xp, hchain, hloc, whobf, whob,
                                     fl_loc, flg3, xcdref, out, hfinal);
}

// Round 10
// 1917.837 us; speedup vs baseline: 1.9719x; 1.9719x over previous
//
#include <hip/hip_runtime.h>
#include <stdint.h>

#define NB 16
#define NS 256
#define NV 32000
#define NE 512
#define NH 1024
#define PAD_IDX 3

// workspace byte offsets (total 27.3 MB -- well under proven ws >= 90.9 MB)
#define WS_XP    0L                 // f32 [4096][1024]        16,777,216 B
#define WS_MIR   16777216L          // bf16 mir[256][16][1024]  8,388,608 B
#define WS_PART  25165824L          // u64 [16][2][1024][8]     2,097,152 B
#define WS_GFL   27262976L          // u8  [256][16][8]            32,768 B
#define WS_NEED  27295744L

typedef __attribute__((ext_vector_type(8))) short bf16x8;
typedef __attribute__((ext_vector_type(4))) float f32x4;
typedef __attribute__((ext_vector_type(4))) uint32_t u32x4;

__device__ __forceinline__ uint16_t f2bf(float f){
  union { float f; uint32_t u; } v; v.f = f;
  return (uint16_t)((v.u + 0x7fffu + ((v.u >> 16) & 1u)) >> 16);  // RNE
}

__device__ __forceinline__ bf16x8 pack8(float4 a, float4 b){
  bf16x8 r;
  r[0]=(short)f2bf(a.x); r[1]=(short)f2bf(a.y); r[2]=(short)f2bf(a.z); r[3]=(short)f2bf(a.w);
  r[4]=(short)f2bf(b.x); r[5]=(short)f2bf(b.y); r[6]=(short)f2bf(b.z); r[7]=(short)f2bf(b.w);
  return r;
}

// device-coherent (L3) ops
__device__ __forceinline__ u32x4 load_coh16(const void* p){
  u32x4 r;
  asm volatile("global_load_dwordx4 %0, %1, off sc0 sc1" : "=v"(r) : "v"(p) : "memory");
  return r;
}
__device__ __forceinline__ uint32_t load_u8_coh(const void* p){
  uint32_t r;
  asm volatile("global_load_ubyte %0, %1, off sc0 sc1" : "=v"(r) : "v"(p) : "memory");
  return r;
}
__device__ __forceinline__ void store_coh8(void* p, uint64_t v){
  asm volatile("global_store_dwordx2 %0, %1, off sc0 sc1" :: "v"(p), "v"(v) : "memory");
}
__device__ __forceinline__ void store_coh4(void* p, uint32_t v){
  asm volatile("global_store_dword %0, %1, off sc0 sc1" :: "v"(p), "v"(v) : "memory");
}
__device__ __forceinline__ void store_u8_coh(void* p, uint32_t v){
  asm volatile("global_store_byte %0, %1, off sc0 sc1" :: "v"(p), "v"(v) : "memory");
}

// clamped fast tanh; abs err ~1e-5, never NaN/inf
__device__ __forceinline__ float tanh_fast(float x){
  x = fminf(fmaxf(x, -10.f), 10.f);
  float t = __builtin_amdgcn_exp2f(x * 2.885390081777927f);  // 2*log2(e)
  return (t - 1.0f) * __builtin_amdgcn_rcpf(t + 1.0f);
}

// ---- K0: zero partial-exchange tags and gate flags
__global__ void k_init(uint32_t* __restrict__ part32, uint32_t* __restrict__ gfl32){
  int idx = blockIdx.x * 256 + threadIdx.x;   // grid 2048*256 = 524288
  if (idx < 524288) part32[idx] = 0u;         // part: 2 MB (tags -> 0, != any t+1)
  if (idx < 8192)   gfl32[idx]  = 0u;         // gfl: 32 KB
}

// ---- K1: xp[m][n] = sum_k emb(ids[m])[k] * Wxh[n][k] + b[n]   (m=b*256+s)
__global__ __launch_bounds__(256) void k_xproj(
    const int* __restrict__ ids, const float* __restrict__ tab,
    const float* __restrict__ wxh, const float* __restrict__ bxh,
    float* __restrict__ xp){
  int bid = blockIdx.x;                 // 64 M-tiles x 16 N-tiles
  int tm = bid & 63, tn = bid >> 6;
  int Mb = tm * 64, Nb = tn * 64;
  int tid = threadIdx.x;
  int w = tid >> 6, l = tid & 63;
  int lr = l & 15, lk = l >> 4;

  int m = Mb + w*16 + lr;
  int id = ids[m];
  const float* arow = tab + (long)id * NE;
  bool pad = (id == PAD_IDX);

  f32x4 acc[4];
  #pragma unroll
  for (int j = 0; j < 4; ++j) acc[j] = (f32x4){0.f,0.f,0.f,0.f};

  for (int k0 = 0; k0 < NE; k0 += 32){
    int k = k0 + lk*8;
    bf16x8 af = (bf16x8){0,0,0,0,0,0,0,0};
    if (!pad){
      float4 a = *(const float4*)(arow + k);
      float4 b = *(const float4*)(arow + k + 4);
      af = pack8(a, b);
    }
    #pragma unroll
    for (int j = 0; j < 4; ++j){
      const float* brow = wxh + (long)(Nb + j*16 + lr) * NE + k;
      float4 x = *(const float4*)brow;
      float4 y = *(const float4*)(brow + 4);
      bf16x8 bf_ = pack8(x, y);
      acc[j] = __builtin_amdgcn_mfma_f32_16x16x32_bf16(af, bf_, acc[j], 0, 0, 0);
    }
  }
  #pragma unroll
  for (int j = 0; j < 4; ++j){
    int n = Nb + j*16 + lr;
    float bias = bxh[n];
    #pragma unroll
    for (int r = 0; r < 4; ++r){
      int row = Mb + w*16 + lk*4 + r;
      xp[(long)row * NH + n] = acc[j][r] + bias;
    }
  }
}

// ---- K2 fused.
// RNN (bids 0..127): 16 per-batch teams x 8 members (256-thr blocks). Member
//   (b,c) owns K-slice [c*128,(c+1)*128); wave w owns outs [w*256,(w+1)*256);
//   Whh slice in 256 VGPR/lane. Per step: MFMA partials (M=16, row0=batch) ->
//   store u64{f32,tag=t+1} (8B atomic: no flag ordering) -> threads 0..127
//   poll their k's 8 entries (64 B contig; own from LDS, 7 tags checked) ->
//   tanh -> h to LDS + bf16 mirror. 2-slot part ping-pong: reuse-safe by
//   induction (producing tag t+1 requires having consumed tag t, which
//   requires everyone produced tag t, which requires everyone consumed t-1).
//   gfl[t] (mir[t] visible) set AFTER the step-(t+1) barrier that postdates
//   both polling waves' vmcnt(0) -- no cross-wave ack race.
// GEMM (bids 128..8127): R6 reg-staged 128x128, s-major M, Who converted
//   f32->bf16 during staging (no precvt pass), gated on gfl[tm*8+7][*][*].
__global__ __launch_bounds__(256, 2) void k_fused(
    const float* __restrict__ whh, const float* __restrict__ xp,
    const float* __restrict__ hidden, uint16_t* __restrict__ mir,
    uint64_t* __restrict__ part, uint8_t* __restrict__ gfl,
    const float* __restrict__ who, const float* __restrict__ whob,
    float* __restrict__ out, float* __restrict__ hfin){
  __shared__ __align__(16) char smem[16*1024 + 1536];
  const int bid = blockIdx.x;
  const int tid = threadIdx.x;

  if (bid < 128){
    // ================= RNN path =================
    const int b = bid >> 3, c = bid & 7;
    const int w = tid >> 6, l = tid & 63;
    const int lr = l & 15, lk = l >> 4;
    const int k0 = c * 128;
    uint16_t* hsb  = (uint16_t*)(smem + 16*1024);        // [2][128] bf16
    float*    pown = (float*)   (smem + 16*1024 + 512);  // [128] f32
    __builtin_amdgcn_s_setprio(2);

    // Whh slice -> 64 bf16x8 = 256 VGPR: W[w*256+g*16+lr][k0+kk*32+lk*8 ..+7]
    bf16x8 wf[64];
    #pragma unroll
    for (int g = 0; g < 16; ++g){
      #pragma unroll
      for (int kk = 0; kk < 4; ++kk){
        const float* s0 = whh + (long)(w*256 + g*16 + lr) * NH + k0 + kk*32 + lk*8;
        wf[g*4+kk] = pack8(*(const float4*)s0, *(const float4*)(s0 + 4));
      }
    }

    if (tid < 128) hsb[tid] = f2bf(hidden[(long)b * NH + k0 + tid]);  // h_0
    __syncthreads();

    uint64_t* pbase = part + (long)b * 2 * 1024 * 8;

    for (int t = 0; t < NS; ++t){
      uint64_t* ps = pbase + (long)(t & 1) * 1024 * 8;
      const uint16_t* hs = hsb + (t & 1) * 128;
      uint16_t* hsn = hsb + ((t + 1) & 1) * 128;
      const uint32_t tg = (uint32_t)(t + 1);

      // A-frags: row 0 = h (lanes lr==0), rows 1..15 zeroed
      bf16x8 a[4];
      #pragma unroll
      for (int kk = 0; kk < 4; ++kk){
        bf16x8 z = (bf16x8){0,0,0,0,0,0,0,0};
        if (lr == 0) z = *(const bf16x8*)&hs[kk*32 + lk*8];
        a[kk] = z;
      }
      // MFMA + tagged partial stores (acc reused per colgroup)
      #pragma unroll
      for (int g = 0; g < 16; ++g){
        f32x4 acc = (f32x4){0.f,0.f,0.f,0.f};
        acc = __builtin_amdgcn_mfma_f32_16x16x32_bf16(a[0], wf[g*4+0], acc, 0, 0, 0);
        acc = __builtin_amdgcn_mfma_f32_16x16x32_bf16(a[1], wf[g*4+1], acc, 0, 0, 0);
        acc = __builtin_amdgcn_mfma_f32_16x16x32_bf16(a[2], wf[g*4+2], acc, 0, 0, 0);
        acc = __builtin_amdgcn_mfma_f32_16x16x32_bf16(a[3], wf[g*4+3], acc, 0, 0, 0);
        if (l < 16){
          int n = w*256 + g*16 + l;
          uint64_t e = ((uint64_t)tg << 32) | (uint64_t)__float_as_uint(acc[0]);
          store_coh8(&ps[(long)n*8 + c], e);
          if (w == (c >> 1) && (g >> 3) == (c & 1)) pown[(g & 7)*16 + l] = acc[0];
        }
      }
      __syncthreads();   // pown ready; hs fully consumed

      if (tid < 128){
        int k = k0 + tid;
        float xpv = xp[((long)b * NS + t) * NH + k];
        const char* pr = (const char*)&ps[(long)k * 8];
        u32x4 v0, v1, v2, v3;
        while (true){
          v0 = load_coh16(pr);      v1 = load_coh16(pr + 16);
          v2 = load_coh16(pr + 32); v3 = load_coh16(pr + 48);
          asm volatile("s_waitcnt vmcnt(0)" ::: "memory");
          __builtin_amdgcn_sched_barrier(0);   // rule #18: pin check after waitcnt
          bool ok = (c==0 || v0[1]==tg) && (c==1 || v0[3]==tg)
                 && (c==2 || v1[1]==tg) && (c==3 || v1[3]==tg)
                 && (c==4 || v2[1]==tg) && (c==5 || v2[3]==tg)
                 && (c==6 || v3[1]==tg) && (c==7 || v3[3]==tg);
          if (__all(ok)) break;
          __builtin_amdgcn_s_sleep(1);
        }
        __builtin_amdgcn_sched_barrier(0);
        float s = xpv + pown[tid];             // own partial from LDS (no self-wait)
        if (c != 0) s += __uint_as_float(v0[0]);
        if (c != 1) s += __uint_as_float(v0[2]);
        if (c != 2) s += __uint_as_float(v1[0]);
        if (c != 3) s += __uint_as_float(v1[2]);
        if (c != 4) s += __uint_as_float(v2[0]);
        if (c != 5) s += __uint_as_float(v2[2]);
        if (c != 6) s += __uint_as_float(v3[0]);
        if (c != 7) s += __uint_as_float(v3[2]);
        float hv = tanh_fast(s);
        if (t == NS-1) hfin[(long)b * NH + k] = hv;
        uint16_t hb16 = f2bf(hv);
        hsn[tid] = hb16;
        uint32_t lo = (uint32_t)hb16;
        uint32_t hi = (uint32_t)__shfl_down((int)lo, 1);
        if (!(tid & 1)){
          char* dm = (char*)mir + (((long)t * NB + b) * NH + k) * 2;
          store_coh4(dm, lo | (hi << 16));     // mir[t] = h_{t+1}
        }
      }
      __syncthreads();   // hsn ready; both polling waves past vmcnt(0)
      // certify mir[t-1]: its stores (step t-1) drained by each wave's own
      // step-t poll vmcnt; barrier above postdates both waves.
      if (tid == 0 && t >= 1) store_u8_coh(gfl + (long)(t-1)*128 + b*8 + c, 1u);
    }
    asm volatile("s_waitcnt vmcnt(0)" ::: "memory");
    __syncthreads();
    if (tid == 0) store_u8_coh(gfl + (long)(NS-1)*128 + b*8 + c, 1u);
    return;
  }

  // ================= logits path (reg-staged, s-major, on-the-fly B cvt) ====
  uint16_t* As = (uint16_t*)smem;          // 8 KB
  uint16_t* Bs = (uint16_t*)(smem + 8192); // 8 KB
  int tile = bid - 128;                    // 0..7999
  int tm = tile / 250;                     // s-group (8 steps per tile)
  int tn = tile % 250;
  int Mb = tm * 128, Nb = tn * 128;
  int hs = tm * 8 + 7;                     // highest needed s

  {  // gate: 128 B of gfl[hs]
    const uint8_t* gp = gfl + (long)hs*128 + (tid & 127);
    while (true){
      uint32_t f = load_u8_coh(gp);
      asm volatile("s_waitcnt vmcnt(0)" ::: "memory");
      __builtin_amdgcn_sched_barrier(0);
      if (__syncthreads_count(f == 0u) == 0) break;
      __builtin_amdgcn_s_sleep(16);
    }
  }

  int wv = tid >> 6, l = tid & 63;
  int wm = wv >> 1, wn = wv & 1;
  int lr = l & 15, lk = l >> 4;

  int r0 = tid >> 2, c0 = tid & 3;
  int r1 = r0 + 64;
  const uint16_t* pa0 = mir + (long)(Mb + r0) * NH + c0*8;   // row m = s*16+b
  const uint16_t* pa1 = mir + (long)(Mb + r1) * NH + c0*8;
  const float* pb0 = who + (long)(Nb + r0) * NH + c0*8;
  const float* pb1 = who + (long)(Nb + r1) * NH + c0*8;
  int da0 = r0*4 + (c0 ^ (r0 & 3));
  int da1 = r1*4 + (c0 ^ (r1 & 3));

  u32x4  ra0 = *(const u32x4*)pa0;
  u32x4  ra1 = *(const u32x4*)pa1;
  float4 f00 = *(const float4*)pb0, f01 = *(const float4*)(pb0 + 4);
  float4 f10 = *(const float4*)pb1, f11 = *(const float4*)(pb1 + 4);

  f32x4 acc[4][4];
  #pragma unroll
  for (int i = 0; i < 4; ++i)
    #pragma unroll
    for (int jj = 0; jj < 4; ++jj) acc[i][jj] = (f32x4){0.f,0.f,0.f,0.f};

  for (int kt = 0; kt < 32; ++kt){
    ((u32x4*)As)[da0] = ra0;
    ((u32x4*)As)[da1] = ra1;
    bf16x8 pb_0 = pack8(f00, f01), pb_1 = pack8(f10, f11);
    ((u32x4*)Bs)[da0] = *(u32x4*)&pb_0;
    ((u32x4*)Bs)[da1] = *(u32x4*)&pb_1;
    __syncthreads();
    if (kt != 31){
      int off = (kt + 1) * 32;
      ra0 = *(const u32x4*)(pa0 + off);
      ra1 = *(const u32x4*)(pa1 + off);
      f00 = *(const float4*)(pb0 + off); f01 = *(const float4*)(pb0 + off + 4);
      f10 = *(const float4*)(pb1 + off); f11 = *(const float4*)(pb1 + off + 4);
    }
    bf16x8 af[4], bg_[4];
    #pragma unroll
    for (int i = 0; i < 4; ++i){
      int ra = wm*64 + i*16 + lr;
      int rb = wn*64 + i*16 + lr;
      af[i]  = *(const bf16x8*)&((const u32x4*)As)[ra*4 + (lk ^ (ra & 3))];
      bg_[i] = *(const bf16x8*)&((const u32x4*)Bs)[rb*4 + (lk ^ (rb & 3))];
    }
    #pragma unroll
    for (int i = 0; i < 4; ++i)
      #pragma unroll
      for (int jj = 0; jj < 4; ++jj)
        acc[i][jj] = __builtin_amdgcn_mfma_f32_16x16x32_bf16(af[i], bg_[jj], acc[i][jj], 0, 0, 0);
    __syncthreads();
  }

  #pragma unroll
  for (int jj = 0; jj < 4; ++jj){
    int col = Nb + wn*64 + jj*16 + lr;
    float bias = whob[col];
    #pragma unroll
    for (int i = 0; i < 4; ++i){
      #pragma unroll
      for (int rr = 0; rr < 4; ++rr){
        int m = Mb + wm*64 + i*16 + lk*4 + rr;      // m = s*16 + b
        long orow = (long)((m & 15) * 256 + (m >> 4));
        out[orow * NV + col] = acc[i][jj][rr] + bias;
      }
    }
  }
}

extern "C" void kernel_launch(void* const* d_in, const int* in_sizes, int n_in,
                              void* d_out, int out_size, void* d_ws, size_t ws_size,
                              hipStream_t stream){
  (void)in_sizes; (void)n_in; (void)out_size;
  if (ws_size < (size_t)WS_NEED) return;   // insufficient scratch -> fail loudly

  const int*   ids    = (const int*)  d_in[0];
  const float* hidden = (const float*)d_in[1];
  const float* table  = (const float*)d_in[2];
  const float* wxh    = (const float*)d_in[3];
  const float* bxh    = (const float*)d_in[4];
  const float* whh    = (const float*)d_in[5];
  const float* who    = (const float*)d_in[6];
  const float* whob   = (const float*)d_in[7];

  char* ws = (char*)d_ws;
  float*    xp   = (float*)   (ws + WS_XP);
  uint16_t* mir  = (uint16_t*)(ws + WS_MIR);
  uint64_t* part = (uint64_t*)(ws + WS_PART);
  uint8_t*  gfl  = (uint8_t*) (ws + WS_GFL);
  float* out    = (float*)d_out;
  float* hfinal = out + (long)NB * NS * NV;   // 131,072,000

  k_init <<<2048, 256, 0, stream>>>((uint32_t*)part, (uint32_t*)gfl);
  k_xproj<<<1024, 256, 0, stream>>>(ids, table, wxh, bxh, xp);
  k_fused<<<8128, 256, 0, stream>>>(whh, xp, hidden, mir, part, gfl,
                                    who, whob, out, hfinal);
}

// Round 11
// 1727.968 us; speedup vs baseline: 2.1886x; 1.1099x over previous
//
#include <hip/hip_runtime.h>
#include <stdint.h>

#define NB 16
#define NS 256
#define NV 32000
#define NE 512
#define NH 1024
#define PAD_IDX 3

// workspace byte offsets
#define WS_XP    0L                 // f32 [4096][1024]   16,777,216 B
#define WS_HCH   16777216L          // bf16 [257][16][1024] 8,421,376 B
#define WS_WHO   25198592L          // bf16 [32000][1024] 65,536,000 B
#define WS_FLG   90734592L          // u32 done[257][64]      65,792 B
#define WS_NEED  90800384L

typedef __attribute__((ext_vector_type(8))) short bf16x8;
typedef __attribute__((ext_vector_type(4))) float f32x4;
typedef __attribute__((ext_vector_type(4))) uint32_t u32x4;

__device__ __forceinline__ uint16_t f2bf(float f){
  union { float f; uint32_t u; } v; v.f = f;
  return (uint16_t)((v.u + 0x7fffu + ((v.u >> 16) & 1u)) >> 16);  // RNE
}

__device__ __forceinline__ bf16x8 pack8(float4 a, float4 b){
  bf16x8 r;
  r[0]=(short)f2bf(a.x); r[1]=(short)f2bf(a.y); r[2]=(short)f2bf(a.z); r[3]=(short)f2bf(a.w);
  r[4]=(short)f2bf(b.x); r[5]=(short)f2bf(b.y); r[6]=(short)f2bf(b.z); r[7]=(short)f2bf(b.w);
  return r;
}

// device-coherent (L3) ops: bypass L1+L2
__device__ __forceinline__ u32x4 load_coh16(const void* p){
  u32x4 r;
  asm volatile("global_load_dwordx4 %0, %1, off sc0 sc1" : "=v"(r) : "v"(p) : "memory");
  return r;
}
__device__ __forceinline__ uint32_t load_coh4(const void* p){
  uint32_t r;
  asm volatile("global_load_dword %0, %1, off sc0 sc1" : "=v"(r) : "v"(p) : "memory");
  return r;
}
__device__ __forceinline__ void store_coh8(void* p, uint64_t v){
  asm volatile("global_store_dwordx2 %0, %1, off sc0 sc1" :: "v"(p), "v"(v) : "memory");
}
__device__ __forceinline__ void store_coh4(void* p, uint32_t v){
  asm volatile("global_store_dword %0, %1, off sc0 sc1" :: "v"(p), "v"(v) : "memory");
}

__device__ __forceinline__ u32x4 umax4(u32x4 a, u32x4 b){
  u32x4 r;
  r[0] = a[0] > b[0] ? a[0] : b[0];
  r[1] = a[1] > b[1] ? a[1] : b[1];
  r[2] = a[2] > b[2] ? a[2] : b[2];
  r[3] = a[3] > b[3] ? a[3] : b[3];
  return r;
}

// clamped fast tanh; abs err ~1e-5, never NaN/inf (|out|<=1 -> bf16 never 0xFFFF)
__device__ __forceinline__ float tanh_fast(float x){
  x = fminf(fmaxf(x, -10.f), 10.f);
  float t = __builtin_amdgcn_exp2f(x * 2.885390081777927f);  // 2*log2(e)
  return (t - 1.0f) * __builtin_amdgcn_rcpf(t + 1.0f);
}

// ---- K0: sentinel-fill hchain slots 1..256, hidden -> slot 0, zero done flags
__global__ void k_init(const float* __restrict__ hidden, uint16_t* __restrict__ hch,
                       uint32_t* __restrict__ done){
  long idx = (long)blockIdx.x * 256 + threadIdx.x;   // grid 2048*256 = 524,288
  ((u32x4*)(hch + (long)NB * NH))[idx] = (u32x4){~0u, ~0u, ~0u, ~0u};
  if (idx < NB * NH) hch[idx] = f2bf(hidden[idx]);
  if (idx < 257 * 64) done[idx] = 0u;
}

// ---- K1: Who_w f32 -> bf16 (row-major [32000][1024])
__global__ void k_cvt(const float* __restrict__ src, uint32_t* __restrict__ dst){
  long idx = (long)blockIdx.x * 256 + threadIdx.x;  // 4,096,000 threads, 8 f32 each
  const float4* p = (const float4*)src;
  float4 a = p[idx*2], b = p[idx*2+1];
  u32x4 d;
  d[0] = (uint32_t)f2bf(a.x) | ((uint32_t)f2bf(a.y) << 16);
  d[1] = (uint32_t)f2bf(a.z) | ((uint32_t)f2bf(a.w) << 16);
  d[2] = (uint32_t)f2bf(b.x) | ((uint32_t)f2bf(b.y) << 16);
  d[3] = (uint32_t)f2bf(b.z) | ((uint32_t)f2bf(b.w) << 16);
  ((u32x4*)dst)[idx] = d;
}

// ---- K2: xp[m][n] = sum_k emb(ids[m])[k] * Wxh[n][k] + b[n]   (m=(b,s), bf16 MFMA)
__global__ __launch_bounds__(256) void k_xproj(
    const int* __restrict__ ids, const float* __restrict__ tab,
    const float* __restrict__ wxh, const float* __restrict__ bxh,
    float* __restrict__ xp){
  int bid = blockIdx.x;                 // 64 M-tiles x 16 N-tiles
  int tm = bid & 63, tn = bid >> 6;
  int Mb = tm * 64, Nb = tn * 64;
  int tid = threadIdx.x;
  int w = tid >> 6, l = tid & 63;
  int lr = l & 15, lk = l >> 4;

  int m = Mb + w*16 + lr;
  int id = ids[m];
  const float* arow = tab + (long)id * NE;
  bool pad = (id == PAD_IDX);

  f32x4 acc[4];
  #pragma unroll
  for (int j = 0; j < 4; ++j) acc[j] = (f32x4){0.f,0.f,0.f,0.f};

  for (int k0 = 0; k0 < NE; k0 += 32){
    int k = k0 + lk*8;
    bf16x8 af = (bf16x8){0,0,0,0,0,0,0,0};
    if (!pad){
      float4 a = *(const float4*)(arow + k);
      float4 b = *(const float4*)(arow + k + 4);
      af = pack8(a, b);
    }
    #pragma unroll
    for (int j = 0; j < 4; ++j){
      const float* brow = wxh + (long)(Nb + j*16 + lr) * NE + k;
      float4 x = *(const float4*)brow;
      float4 y = *(const float4*)(brow + 4);
      bf16x8 bf_ = pack8(x, y);
      acc[j] = __builtin_amdgcn_mfma_f32_16x16x32_bf16(af, bf_, acc[j], 0, 0, 0);
    }
  }
  #pragma unroll
  for (int j = 0; j < 4; ++j){
    int n = Nb + j*16 + lr;
    float bias = bxh[n];
    #pragma unroll
    for (int r = 0; r < 4; ++r){
      int row = Mb + w*16 + lk*4 + r;
      xp[(long)row * NH + n] = acc[j][r] + bias;
    }
  }
}

// ---- K3 fused.
// RNN (bids 0..63): R4's 1-wave col-split (block owns 16 cols, Whh in LDS,
//   sentinel data-poll) + PROBE-SPLIT poll: poll only frags kk=0,4,...,28
//   (128 B/lane, samples 16 of 64 producers) -> short retry trip; on pass,
//   issue 24 tail loads, MFMA the probe frags in their shadow, then
//   sentinel-check the tail (rarely retries) and MFMA it. done[t][role]
//   certification folded into the first probe vmcnt (R6 protocol).
// GEMM (bids 64..8063): R6 reg-staged 128x128, s-major M-tiles (tile tm spans
//   8 steps), bf16 whobf, gated on done[tm*8+8][0..63].
__global__ __launch_bounds__(256, 2) void k_fused(
    const float* __restrict__ whh, const float* __restrict__ xp,
    uint16_t* __restrict__ hch, const uint16_t* __restrict__ whobf,
    const float* __restrict__ whob, uint32_t* __restrict__ done,
    float* __restrict__ out, float* __restrict__ hfin){
  __shared__ __align__(16) char smem[33*1024 + 1024];
  const int bid = blockIdx.x;
  const int tid = threadIdx.x;

  if (bid < 64){
    // ================= RNN path (1 wave) =================
    if (tid >= 64) return;
    uint16_t* whh_s = (uint16_t*)smem;                 // 32 KB, xor-swizzled
    uint16_t* hs2   = (uint16_t*)(smem + 33*1024);     // [2][256] double buffer
    const int role = bid;
    const int l    = tid;
    const int j0   = role * 16;
    const int lr = l & 15, lk = l >> 4;
    __builtin_amdgcn_s_setprio(2);

    // stage Whh rows [j0, j0+16) as bf16, swizzle chunk c -> c^(row&7)
    for (int it = 0; it < 32; ++it){
      int chunk = it*64 + l;        // 0..2047 = row*128 + c
      int row = chunk >> 7, c = chunk & 127;
      const float* s0 = whh + (long)(j0 + row) * NH + c*8;
      float4 a = *(const float4*)s0;
      float4 b = *(const float4*)(s0 + 4);
      u32x4 d;
      d[0] = (uint32_t)f2bf(a.x) | ((uint32_t)f2bf(a.y) << 16);
      d[1] = (uint32_t)f2bf(a.z) | ((uint32_t)f2bf(a.w) << 16);
      d[2] = (uint32_t)f2bf(b.x) | ((uint32_t)f2bf(b.y) << 16);
      d[3] = (uint32_t)f2bf(b.z) | ((uint32_t)f2bf(b.w) << 16);
      ((u32x4*)whh_s)[row*128 + (c ^ (row & 7))] = d;
    }
    asm volatile("s_waitcnt lgkmcnt(0)" ::: "memory");
    __builtin_amdgcn_sched_barrier(0);

    float xpreg[4];
    #pragma unroll
    for (int r = 0; r < 4; ++r)
      xpreg[r] = xp[((long)(lk*4 + r) * NS + 0) * NH + j0 + lr];

    const char* hbase = (const char*)hch;
    for (int t = 0; t < NS; ++t){
      const char* hsrc = hbase + (long)t * NB * NH * 2 + lr * 2048 + lk * 16;
      u32x4 hfrag[32];
      bool first = true;

      // ---- probe poll: frags kk = 0,4,8,...,28 (16 of 64 producers sampled)
      while (true){
        #pragma unroll
        for (int q = 0; q < 8; ++q)
          hfrag[q*4] = load_coh16(hsrc + (q*4) * 64);
        asm volatile("s_waitcnt vmcnt(0)" ::: "memory");
        __builtin_amdgcn_sched_barrier(0);   // rule #18: pin check after waitcnt
        if (first){
          // our slot-t stores (issued at step t-1) just drained -> certify
          if (l == 0 && t > 0) store_coh4(done + t*64 + role, 1u);
          first = false;
        }
        u32x4 m4 = hfrag[0];
        #pragma unroll
        for (int q = 1; q < 8; ++q) m4 = umax4(m4, hfrag[q*4]);
        uint32_t m01 = m4[0] > m4[1] ? m4[0] : m4[1];
        uint32_t m23 = m4[2] > m4[3] ? m4[2] : m4[3];
        uint32_t m = m01 > m23 ? m01 : m23;
        if (__all(m != 0xFFFFFFFFu)) break;
      }
      __builtin_amdgcn_sched_barrier(0);

      // ---- issue tail loads (24 frags), MFMA probe frags in their shadow
      #pragma unroll
      for (int q = 0; q < 8; ++q){
        hfrag[q*4+1] = load_coh16(hsrc + (q*4+1) * 64);
        hfrag[q*4+2] = load_coh16(hsrc + (q*4+2) * 64);
        hfrag[q*4+3] = load_coh16(hsrc + (q*4+3) * 64);
      }
      f32x4 a0 = (f32x4){0.f,0.f,0.f,0.f}, a1 = a0, a2 = a0, a3 = a0;
      #pragma unroll
      for (int q = 0; q < 8; ++q){
        int c0 = (q*4)*4 + lk;     // LDS chunk col for frag q*4
        bf16x8 b0 = *(const bf16x8*)&((const u32x4*)whh_s)[lr*128 + (c0 ^ (lr & 7))];
        a0 = __builtin_amdgcn_mfma_f32_16x16x32_bf16(*(const bf16x8*)&hfrag[q*4], b0, a0, 0, 0, 0);
      }
      // ---- tail sentinel check (first pass nearly always clean)
      while (true){
        asm volatile("s_waitcnt vmcnt(0)" ::: "memory");
        __builtin_amdgcn_sched_barrier(0);
        u32x4 m4 = hfrag[1];
        #pragma unroll
        for (int q = 0; q < 8; ++q){
          if (q) m4 = umax4(m4, hfrag[q*4+1]);
          m4 = umax4(m4, hfrag[q*4+2]);
          m4 = umax4(m4, hfrag[q*4+3]);
        }
        uint32_t m01 = m4[0] > m4[1] ? m4[0] : m4[1];
        uint32_t m23 = m4[2] > m4[3] ? m4[2] : m4[3];
        uint32_t m = m01 > m23 ? m01 : m23;
        if (__all(m != 0xFFFFFFFFu)) break;
        #pragma unroll
        for (int q = 0; q < 8; ++q){
          hfrag[q*4+1] = load_coh16(hsrc + (q*4+1) * 64);
          hfrag[q*4+2] = load_coh16(hsrc + (q*4+2) * 64);
          hfrag[q*4+3] = load_coh16(hsrc + (q*4+3) * 64);
        }
      }
      __builtin_amdgcn_sched_barrier(0);
      #pragma unroll
      for (int q = 0; q < 8; ++q){
        int c1 = (q*4+1)*4 + lk, c2 = (q*4+2)*4 + lk, c3 = (q*4+3)*4 + lk;
        bf16x8 b1 = *(const bf16x8*)&((const u32x4*)whh_s)[lr*128 + (c1 ^ (lr & 7))];
        bf16x8 b2 = *(const bf16x8*)&((const u32x4*)whh_s)[lr*128 + (c2 ^ (lr & 7))];
        bf16x8 b3 = *(const bf16x8*)&((const u32x4*)whh_s)[lr*128 + (c3 ^ (lr & 7))];
        a1 = __builtin_amdgcn_mfma_f32_16x16x32_bf16(*(const bf16x8*)&hfrag[q*4+1], b1, a1, 0, 0, 0);
        a2 = __builtin_amdgcn_mfma_f32_16x16x32_bf16(*(const bf16x8*)&hfrag[q*4+2], b2, a2, 0, 0, 0);
        a3 = __builtin_amdgcn_mfma_f32_16x16x32_bf16(*(const bf16x8*)&hfrag[q*4+3], b3, a3, 0, 0, 0);
      }
      f32x4 acc = (a0 + a1) + (a2 + a3);

      // tanh + transpose through LDS double buffer (C/D: row=(l>>4)*4+r, col=l&15)
      uint16_t* hb = hs2 + (t & 1)*256;
      #pragma unroll
      for (int r = 0; r < 4; ++r){
        int b = lk*4 + r;
        float hv = tanh_fast(xpreg[r] + acc[r]);
        hb[b*16 + lr] = f2bf(hv);
        if (t == NS-1) hfin[b*NH + j0 + lr] = hv;
      }
      asm volatile("s_waitcnt lgkmcnt(0)" ::: "memory");
      __builtin_amdgcn_sched_barrier(0);

      {  // coalesced write-through store of slot t+1 slice (fire-and-forget)
        int rb = l >> 2, cc = l & 3;
        uint32_t w0 = *(const uint32_t*)&hb[rb*16 + cc*4];
        uint32_t w1 = *(const uint32_t*)&hb[rb*16 + cc*4 + 2];
        char* dst = (char*)hch + (long)(t+1) * NB * NH * 2 + rb * 2048 + j0*2 + cc*8;
        store_coh8(dst, ((uint64_t)w1 << 32) | (uint64_t)w0);
      }

      if (t + 1 < NS){
        #pragma unroll
        for (int r = 0; r < 4; ++r)
          xpreg[r] = xp[((long)(lk*4 + r) * NS + (t+1)) * NH + j0 + lr];
      }
    }
    asm volatile("s_waitcnt vmcnt(0)" ::: "memory");   // slot-256 stores acked
    if (l == 0) store_coh4(done + NS*64 + role, 1u);
    return;
  }

  // ================= logits path (R6 engine: reg-staged, s-major) ===========
  uint16_t* As = (uint16_t*)smem;          // 8 KB
  uint16_t* Bs = (uint16_t*)(smem + 8192); // 8 KB
  int tile = bid - 64;                     // 0..7999
  int tm = tile / 250;                     // s-group (8 steps per tile)
  int tn = tile % 250;
  int Mb = tm * 128, Nb = tn * 128;
  int hs = tm * 8 + 8;                     // highest needed slot

  {  // flag gate: 64 x u32 of done[hs]
    const uint32_t* gp = done + hs*64 + (tid & 63);
    while (true){
      uint32_t f = load_coh4(gp);
      asm volatile("s_waitcnt vmcnt(0)" ::: "memory");
      __builtin_amdgcn_sched_barrier(0);
      if (__syncthreads_count(f == 0u) == 0) break;
      __builtin_amdgcn_s_sleep(16);
    }
  }

  int wv = tid >> 6, l = tid & 63;
  int wm = wv >> 1, wn = wv & 1;
  int lr = l & 15, lk = l >> 4;

  int r0 = tid >> 2, c0 = tid & 3;
  int r1 = r0 + 64;
  // s-major: A row m <-> hchain row m+16 (contiguous)
  const uint16_t* pa0 = hch + (long)(Mb + r0 + 16) * NH + c0*8;
  const uint16_t* pa1 = hch + (long)(Mb + r1 + 16) * NH + c0*8;
  const uint16_t* pb0 = whobf + (long)(Nb + r0) * NH + c0*8;
  const uint16_t* pb1 = whobf + (long)(Nb + r1) * NH + c0*8;
  int da0 = r0*4 + (c0 ^ (r0 & 3));
  int da1 = r1*4 + (c0 ^ (r1 & 3));

  u32x4 ra0 = *(const u32x4*)pa0;
  u32x4 ra1 = *(const u32x4*)pa1;
  u32x4 rb0 = *(const u32x4*)pb0;
  u32x4 rb1 = *(const u32x4*)pb1;

  f32x4 acc[4][4];
  #pragma unroll
  for (int i = 0; i < 4; ++i)
    #pragma unroll
    for (int jj = 0; jj < 4; ++jj) acc[i][jj] = (f32x4){0.f,0.f,0.f,0.f};

  for (int kt = 0; kt < 32; ++kt){
    ((u32x4*)As)[da0] = ra0;
    ((u32x4*)As)[da1] = ra1;
    ((u32x4*)Bs)[da0] = rb0;
    ((u32x4*)Bs)[da1] = rb1;
    __syncthreads();
    if (kt != 31){
      int off = (kt + 1) * 32;
      ra0 = *(const u32x4*)(pa0 + off);
      ra1 = *(const u32x4*)(pa1 + off);
      rb0 = *(const u32x4*)(pb0 + off);
      rb1 = *(const u32x4*)(pb1 + off);
    }
    bf16x8 af[4], bg_[4];
    #pragma unroll
    for (int i = 0; i < 4; ++i){
      int ra = wm*64 + i*16 + lr;
      int rb = wn*64 + i*16 + lr;
      af[i]  = *(const bf16x8*)&((const u32x4*)As)[ra*4 + (lk ^ (ra & 3))];
      bg_[i] = *(const bf16x8*)&((const u32x4*)Bs)[rb*4 + (lk ^ (rb & 3))];
    }
    #pragma unroll
    for (int i = 0; i < 4; ++i)
      #pragma unroll
      for (int jj = 0; jj < 4; ++jj)
        acc[i][jj] = __builtin_amdgcn_mfma_f32_16x16x32_bf16(af[i], bg_[jj], acc[i][jj], 0, 0, 0);
    __syncthreads();
  }

  #pragma unroll
  for (int jj = 0; jj < 4; ++jj){
    int col = Nb + wn*64 + jj*16 + lr;
    float bias = whob[col];
    #pragma unroll
    for (int i = 0; i < 4; ++i){
      #pragma unroll
      for (int rr = 0; rr < 4; ++rr){
        int m = Mb + wm*64 + i*16 + lk*4 + rr;      // m = s*16 + b
        long orow = (long)((m & 15) * 256 + (m >> 4));
        out[orow * NV + col] = acc[i][jj][rr] + bias;
      }
    }
  }
}

extern "C" void kernel_launch(void* const* d_in, const int* in_sizes, int n_in,
                              void* d_out, int out_size, void* d_ws, size_t ws_size,
                              hipStream_t stream){
  (void)in_sizes; (void)n_in; (void)out_size;
  if (ws_size < (size_t)WS_NEED) return;   // insufficient scratch -> fail loudly

  const int*   ids    = (const int*)  d_in[0];
  const float* hidden = (const float*)d_in[1];
  const float* table  = (const float*)d_in[2];
  const float* wxh    = (const float*)d_in[3];
  const float* bxh    = (const float*)d_in[4];
  const float* whh    = (const float*)d_in[5];
  const float* who    = (const float*)d_in[6];
  const float* whob   = (const float*)d_in[7];

  char* ws = (char*)d_ws;
  float*    xp     = (float*)   (ws + WS_XP);
  uint16_t* hchain = (uint16_t*)(ws + WS_HCH);
  uint16_t* whobf  = (uint16_t*)(ws + WS_WHO);
  uint32_t* done   = (uint32_t*)(ws + WS_FLG);
  float* out    = (float*)d_out;
  float* hfinal = out + (long)NB * NS * NV;   // 131,072,000

  k_init <<<2048,  256, 0, stream>>>(hidden, hchain, done);
  k_cvt  <<<16000, 256, 0, stream>>>(who, (uint32_t*)whobf);
  k_xproj<<<1024,  256, 0, stream>>>(ids, table, wxh, bxh, xp);
  k_fused<<<8064,  256, 0, stream>>>(whh, xp, hchain, whobf, whob, done, out, hfinal);
}

// Round 12
// 1156.890 us; speedup vs baseline: 3.2689x; 1.4936x over previous
//
#include <hip/hip_runtime.h>
#include <stdint.h>

#define NB 16
#define NS 256
#define NV 32000
#define NE 512
#define NH 1024
#define PAD_IDX 3

// workspace byte offsets
#define WS_XP    0L                 // f32 [4096][1024]   16,777,216 B
#define WS_HCH   16777216L          // bf16 [257][16][1024] 8,421,376 B
#define WS_WHO   25198592L          // bf16 [32000][1024] 65,536,000 B
#define WS_FLG   90734592L          // u32 allvis[260] + fin[64]
#define WS_NEED  90800384L

typedef __attribute__((ext_vector_type(8))) short bf16x8;
typedef __attribute__((ext_vector_type(4))) float f32x4;
typedef __attribute__((ext_vector_type(4))) uint32_t u32x4;

__device__ __forceinline__ uint16_t f2bf(float f){
  union { float f; uint32_t u; } v; v.f = f;
  return (uint16_t)((v.u + 0x7fffu + ((v.u >> 16) & 1u)) >> 16);  // RNE
}

__device__ __forceinline__ bf16x8 pack8(float4 a, float4 b){
  bf16x8 r;
  r[0]=(short)f2bf(a.x); r[1]=(short)f2bf(a.y); r[2]=(short)f2bf(a.z); r[3]=(short)f2bf(a.w);
  r[4]=(short)f2bf(b.x); r[5]=(short)f2bf(b.y); r[6]=(short)f2bf(b.z); r[7]=(short)f2bf(b.w);
  return r;
}

// device-coherent (L3) ops: bypass L1+L2
__device__ __forceinline__ u32x4 load_coh16(const void* p){
  u32x4 r;
  asm volatile("global_load_dwordx4 %0, %1, off sc0 sc1" : "=v"(r) : "v"(p) : "memory");
  return r;
}
__device__ __forceinline__ uint32_t load_coh4(const void* p){
  uint32_t r;
  asm volatile("global_load_dword %0, %1, off sc0 sc1" : "=v"(r) : "v"(p) : "memory");
  return r;
}
__device__ __forceinline__ void store_coh8(void* p, uint64_t v){
  asm volatile("global_store_dwordx2 %0, %1, off sc0 sc1" :: "v"(p), "v"(v) : "memory");
}
__device__ __forceinline__ void store_coh4(void* p, uint32_t v){
  asm volatile("global_store_dword %0, %1, off sc0 sc1" :: "v"(p), "v"(v) : "memory");
}
// non-temporal store: don't pollute L3 with the 524 MB out stream
__device__ __forceinline__ void store_nt4(void* p, float v){
  asm volatile("global_store_dword %0, %1, off nt" :: "v"(p), "v"(v) : "memory");
}

__device__ __forceinline__ u32x4 umax4(u32x4 a, u32x4 b){
  u32x4 r;
  r[0] = a[0] > b[0] ? a[0] : b[0];
  r[1] = a[1] > b[1] ? a[1] : b[1];
  r[2] = a[2] > b[2] ? a[2] : b[2];
  r[3] = a[3] > b[3] ? a[3] : b[3];
  return r;
}

// clamped fast tanh; abs err ~1e-5, never NaN/inf (|out|<=1 -> bf16 never 0xFFFF)
__device__ __forceinline__ float tanh_fast(float x){
  x = fminf(fmaxf(x, -10.f), 10.f);
  float t = __builtin_amdgcn_exp2f(x * 2.885390081777927f);  // 2*log2(e)
  return (t - 1.0f) * __builtin_amdgcn_rcpf(t + 1.0f);
}

// ---- K0: sentinel-fill hchain slots 1..256, hidden -> slot 0, zero flags
__global__ void k_init(const float* __restrict__ hidden, uint16_t* __restrict__ hch,
                       uint32_t* __restrict__ flg){
  long idx = (long)blockIdx.x * 256 + threadIdx.x;   // grid 2048*256 = 524,288
  ((u32x4*)(hch + (long)NB * NH))[idx] = (u32x4){~0u, ~0u, ~0u, ~0u};
  if (idx < NB * NH) hch[idx] = f2bf(hidden[idx]);
  if (idx < 512) flg[idx] = 0u;                      // allvis[260] + fin[64]
}

// ---- K1: Who_w f32 -> bf16 (row-major [32000][1024])
__global__ void k_cvt(const float* __restrict__ src, uint32_t* __restrict__ dst){
  long idx = (long)blockIdx.x * 256 + threadIdx.x;  // 4,096,000 threads, 8 f32 each
  const float4* p = (const float4*)src;
  float4 a = p[idx*2], b = p[idx*2+1];
  u32x4 d;
  d[0] = (uint32_t)f2bf(a.x) | ((uint32_t)f2bf(a.y) << 16);
  d[1] = (uint32_t)f2bf(a.z) | ((uint32_t)f2bf(a.w) << 16);
  d[2] = (uint32_t)f2bf(b.x) | ((uint32_t)f2bf(b.y) << 16);
  d[3] = (uint32_t)f2bf(b.z) | ((uint32_t)f2bf(b.w) << 16);
  ((u32x4*)dst)[idx] = d;
}

// ---- K2: xp[m][n] = sum_k emb(ids[m])[k] * Wxh[n][k] + b[n]   (m=(b,s), bf16 MFMA)
__global__ __launch_bounds__(256) void k_xproj(
    const int* __restrict__ ids, const float* __restrict__ tab,
    const float* __restrict__ wxh, const float* __restrict__ bxh,
    float* __restrict__ xp){
  int bid = blockIdx.x;                 // 64 M-tiles x 16 N-tiles
  int tm = bid & 63, tn = bid >> 6;
  int Mb = tm * 64, Nb = tn * 64;
  int tid = threadIdx.x;
  int w = tid >> 6, l = tid & 63;
  int lr = l & 15, lk = l >> 4;

  int m = Mb + w*16 + lr;
  int id = ids[m];
  const float* arow = tab + (long)id * NE;
  bool pad = (id == PAD_IDX);

  f32x4 acc[4];
  #pragma unroll
  for (int j = 0; j < 4; ++j) acc[j] = (f32x4){0.f,0.f,0.f,0.f};

  for (int k0 = 0; k0 < NE; k0 += 32){
    int k = k0 + lk*8;
    bf16x8 af = (bf16x8){0,0,0,0,0,0,0,0};
    if (!pad){
      float4 a = *(const float4*)(arow + k);
      float4 b = *(const float4*)(arow + k + 4);
      af = pack8(a, b);
    }
    #pragma unroll
    for (int j = 0; j < 4; ++j){
      const float* brow = wxh + (long)(Nb + j*16 + lr) * NE + k;
      float4 x = *(const float4*)brow;
      float4 y = *(const float4*)(brow + 4);
      bf16x8 bf_ = pack8(x, y);
      acc[j] = __builtin_amdgcn_mfma_f32_16x16x32_bf16(af, bf_, acc[j], 0, 0, 0);
    }
  }
  #pragma unroll
  for (int j = 0; j < 4; ++j){
    int n = Nb + j*16 + lr;
    float bias = bxh[n];
    #pragma unroll
    for (int r = 0; r < 4; ++r){
      int row = Mb + w*16 + lk*4 + r;
      xp[(long)row * NH + n] = acc[j][r] + bias;
    }
  }
}

// ---- K3 fused (R6 structure + allvis gating + nt out stores + setprio).
// RNN (bids 0..63): 2 waves split-K (wave w owns K-half w, Whh half in 64
//   VGPR); per step one sentinel data-poll (16 coherent 16B frags), partial
//   combine via LDS ping-pong, tanh, coalesced write-through store of slot
//   t+1. Block 0 publishes allvis[t]=1 after its post-poll barrier: its poll
//   pass proves ALL of slot t is at L3 (it read every byte) -> single-flag
//   gate for the GEMM. Final slot 256 certified per-block via fin[role].
// GEMM (bids 64..8063): reg-staged 128x128, s-major M (tile tm spans 8 steps),
//   gated on allvis[tm*8+8] (4 B, one shared line) or fin[0..63] for tm=31;
//   out written with nt to keep whobf L3-resident.
__global__ __launch_bounds__(256, 2) void k_fused(
    const float* __restrict__ whh, const float* __restrict__ xp,
    uint16_t* __restrict__ hch, const uint16_t* __restrict__ whobf,
    const float* __restrict__ whob, uint32_t* __restrict__ allvis,
    uint32_t* __restrict__ fin, float* __restrict__ out,
    float* __restrict__ hfin){
  __shared__ __align__(16) char smem[17*1024];
  const int bid = blockIdx.x;
  const int tid = threadIdx.x;

  if (bid < 64){
    // ================= RNN path (2 waves, split-K) =================
    if (tid >= 128) return;
    float*    accbuf = (float*)smem;                 // [2][64][4] f32, 2 KB
    uint16_t* hs2    = (uint16_t*)(smem + 2048);     // [2][256] bf16, 1 KB
    const int wv = tid >> 6;        // 0 or 1 (K-half)
    const int l  = tid & 63;
    const int j0 = bid * 16;
    const int lr = l & 15, lk = l >> 4;
    __builtin_amdgcn_s_setprio(2);

    // Whh fragments for this wave's K-half -> registers (64 VGPR)
    bf16x8 bfrag[16];
    #pragma unroll
    for (int kk = 0; kk < 16; ++kk){
      const float* s0 = whh + (long)(j0 + lr) * NH + (wv*16 + kk)*32 + lk*8;
      float4 a = *(const float4*)s0;
      float4 b = *(const float4*)(s0 + 4);
      bfrag[kk] = pack8(a, b);
    }

    float xpreg[4];
    if (wv == 0){
      #pragma unroll
      for (int r = 0; r < 4; ++r)
        xpreg[r] = xp[((long)(lk*4 + r) * NS + 0) * NH + j0 + lr];
    }

    const char* hbase = (const char*)hch;
    for (int t = 0; t < NS; ++t){
      // poll this wave's K-half of slot t: h[batch=lr][k = (wv*16+kk)*32 + lk*8]
      const char* hsrc = hbase + (long)t * NB * NH * 2 + lr * 2048 + wv * 1024 + lk * 16;
      u32x4 hfrag[16];
      while (true){
        #pragma unroll
        for (int kk = 0; kk < 16; ++kk)
          hfrag[kk] = load_coh16(hsrc + kk * 64);
        asm volatile("s_waitcnt vmcnt(0)" ::: "memory");
        __builtin_amdgcn_sched_barrier(0);   // pin check AFTER waitcnt (rule #18)
        u32x4 m4 = hfrag[0];
        #pragma unroll
        for (int kk = 1; kk < 16; ++kk) m4 = umax4(m4, hfrag[kk]);
        uint32_t m01 = m4[0] > m4[1] ? m4[0] : m4[1];
        uint32_t m23 = m4[2] > m4[3] ? m4[2] : m4[3];
        uint32_t m = m01 > m23 ? m01 : m23;
        if (__all(m != 0xFFFFFFFFu)) break;
      }
      __builtin_amdgcn_sched_barrier(0);

      f32x4 a0 = (f32x4){0.f,0.f,0.f,0.f}, a1 = a0, a2 = a0, a3 = a0;
      #pragma unroll
      for (int kk = 0; kk < 16; kk += 4){
        a0 = __builtin_amdgcn_mfma_f32_16x16x32_bf16(*(const bf16x8*)&hfrag[kk  ], bfrag[kk  ], a0, 0, 0, 0);
        a1 = __builtin_amdgcn_mfma_f32_16x16x32_bf16(*(const bf16x8*)&hfrag[kk+1], bfrag[kk+1], a1, 0, 0, 0);
        a2 = __builtin_amdgcn_mfma_f32_16x16x32_bf16(*(const bf16x8*)&hfrag[kk+2], bfrag[kk+2], a2, 0, 0, 0);
        a3 = __builtin_amdgcn_mfma_f32_16x16x32_bf16(*(const bf16x8*)&hfrag[kk+3], bfrag[kk+3], a3, 0, 0, 0);
      }
      f32x4 acc = (a0 + a1) + (a2 + a3);

      if (wv == 1)
        *(f32x4*)&accbuf[((t & 1)*64 + l)*4] = acc;   // partial -> wave0
      __syncthreads();   // both waves' polls passed; slot t fully read

      if (wv == 0){
        // block 0's poll pass proves ALL of slot t is at L3 -> publish
        if (bid == 0 && l == 0) store_coh4(allvis + t, 1u);
        f32x4 o = *(const f32x4*)&accbuf[((t & 1)*64 + l)*4];
        uint16_t* hb = hs2 + (t & 1)*256;
        #pragma unroll
        for (int r = 0; r < 4; ++r){
          int b = lk*4 + r;                           // C/D: row=(l>>4)*4+r, col=l&15
          float hv = tanh_fast(xpreg[r] + acc[r] + o[r]);
          hb[b*16 + lr] = f2bf(hv);
          if (t == NS-1) hfin[b*NH + j0 + lr] = hv;
        }
        asm volatile("s_waitcnt lgkmcnt(0)" ::: "memory");
        __builtin_amdgcn_sched_barrier(0);
        // coalesced write-through store of slot t+1 slice (fire-and-forget)
        int rb = l >> 2, cc = l & 3;
        uint32_t w0 = *(const uint32_t*)&hb[rb*16 + cc*4];
        uint32_t w1 = *(const uint32_t*)&hb[rb*16 + cc*4 + 2];
        char* dst = (char*)hch + (long)(t+1) * NB * NH * 2 + rb * 2048 + j0*2 + cc*8;
        store_coh8(dst, ((uint64_t)w1 << 32) | (uint64_t)w0);
        if (t + 1 < NS){
          #pragma unroll
          for (int r = 0; r < 4; ++r)
            xpreg[r] = xp[((long)(lk*4 + r) * NS + (t+1)) * NH + j0 + lr];
        }
      }
    }
    if (wv == 0){
      asm volatile("s_waitcnt vmcnt(0)" ::: "memory");   // slot-256 stores acked
      if (l == 0) store_coh4(fin + bid, 1u);
    }
    return;
  }

  // ================= logits path (reg-staged, s-major tiles) =================
  uint16_t* As = (uint16_t*)smem;          // 8 KB
  uint16_t* Bs = (uint16_t*)(smem + 8192); // 8 KB
  int tile = bid - 64;                     // 0..7999
  int tm = tile / 250;                     // s-group (8 steps per tile)
  int tn = tile % 250;
  int Mb = tm * 128, Nb = tn * 128;
  int hs = tm * 8 + 8;                     // highest needed slot

  if (hs < 256){                           // gate: ONE u32 (shared line)
    while (true){
      uint32_t f = load_coh4(allvis + hs);
      asm volatile("s_waitcnt vmcnt(0)" ::: "memory");
      __builtin_amdgcn_sched_barrier(0);
      if (__syncthreads_count(f == 0u) == 0) break;
      __builtin_amdgcn_s_sleep(16);
    }
  } else {                                 // last s-group: 64 per-block finals
    const uint32_t* gp = fin + (tid & 63);
    while (true){
      uint32_t f = load_coh4(gp);
      asm volatile("s_waitcnt vmcnt(0)" ::: "memory");
      __builtin_amdgcn_sched_barrier(0);
      if (__syncthreads_count(f == 0u) == 0) break;
      __builtin_amdgcn_s_sleep(16);
    }
  }

  int wv = tid >> 6, l = tid & 63;
  int wm = wv >> 1, wn = wv & 1;
  int lr = l & 15, lk = l >> 4;

  int r0 = tid >> 2, c0 = tid & 3;
  int r1 = r0 + 64;
  // s-major: A row m <-> hchain row m+16 (contiguous)
  const uint16_t* pa0 = hch + (long)(Mb + r0 + 16) * NH + c0*8;
  const uint16_t* pa1 = hch + (long)(Mb + r1 + 16) * NH + c0*8;
  const uint16_t* pb0 = whobf + (long)(Nb + r0) * NH + c0*8;
  const uint16_t* pb1 = whobf + (long)(Nb + r1) * NH + c0*8;
  int da0 = r0*4 + (c0 ^ (r0 & 3));
  int da1 = r1*4 + (c0 ^ (r1 & 3));

  u32x4 ra0 = *(const u32x4*)pa0;
  u32x4 ra1 = *(const u32x4*)pa1;
  u32x4 rb0 = *(const u32x4*)pb0;
  u32x4 rb1 = *(const u32x4*)pb1;

  f32x4 acc[4][4];
  #pragma unroll
  for (int i = 0; i < 4; ++i)
    #pragma unroll
    for (int jj = 0; jj < 4; ++jj) acc[i][jj] = (f32x4){0.f,0.f,0.f,0.f};

  for (int kt = 0; kt < 32; ++kt){
    ((u32x4*)As)[da0] = ra0;
    ((u32x4*)As)[da1] = ra1;
    ((u32x4*)Bs)[da0] = rb0;
    ((u32x4*)Bs)[da1] = rb1;
    __syncthreads();
    if (kt != 31){
      int off = (kt + 1) * 32;
      ra0 = *(const u32x4*)(pa0 + off);
      ra1 = *(const u32x4*)(pa1 + off);
      rb0 = *(const u32x4*)(pb0 + off);
      rb1 = *(const u32x4*)(pb1 + off);
    }
    bf16x8 af[4], bg_[4];
    #pragma unroll
    for (int i = 0; i < 4; ++i){
      int ra = wm*64 + i*16 + lr;
      int rb = wn*64 + i*16 + lr;
      af[i]  = *(const bf16x8*)&((const u32x4*)As)[ra*4 + (lk ^ (ra & 3))];
      bg_[i] = *(const bf16x8*)&((const u32x4*)Bs)[rb*4 + (lk ^ (rb & 3))];
    }
    #pragma unroll
    for (int i = 0; i < 4; ++i)
      #pragma unroll
      for (int jj = 0; jj < 4; ++jj)
        acc[i][jj] = __builtin_amdgcn_mfma_f32_16x16x32_bf16(af[i], bg_[jj], acc[i][jj], 0, 0, 0);
    __syncthreads();
  }

  #pragma unroll
  for (int jj = 0; jj < 4; ++jj){
    int col = Nb + wn*64 + jj*16 + lr;
    float bias = whob[col];
    #pragma unroll
    for (int i = 0; i < 4; ++i){
      #pragma unroll
      for (int rr = 0; rr < 4; ++rr){
        int m = Mb + wm*64 + i*16 + lk*4 + rr;      // m = s*16 + b
        long orow = (long)((m & 15) * 256 + (m >> 4));
        store_nt4(&out[orow * NV + col], acc[i][jj][rr] + bias);
      }
    }
  }
}

extern "C" void kernel_launch(void* const* d_in, const int* in_sizes, int n_in,
                              void* d_out, int out_size, void* d_ws, size_t ws_size,
                              hipStream_t stream){
  (void)in_sizes; (void)n_in; (void)out_size;
  if (ws_size < (size_t)WS_NEED) return;   // insufficient scratch -> fail loudly

  const int*   ids    = (const int*)  d_in[0];
  const float* hidden = (const float*)d_in[1];
  const float* table  = (const float*)d_in[2];
  const float* wxh    = (const float*)d_in[3];
  const float* bxh    = (const float*)d_in[4];
  const float* whh    = (const float*)d_in[5];
  const float* who    = (const float*)d_in[6];
  const float* whob   = (const float*)d_in[7];

  char* ws = (char*)d_ws;
  float*    xp     = (float*)   (ws + WS_XP);
  uint16_t* hchain = (uint16_t*)(ws + WS_HCH);
  uint16_t* whobf  = (uint16_t*)(ws + WS_WHO);
  uint32_t* allvis = (uint32_t*)(ws + WS_FLG);     // [260]
  uint32_t* fin    = allvis + 260;                 // [64]
  float* out    = (float*)d_out;
  float* hfinal = out + (long)NB * NS * NV;   // 131,072,000

  k_init <<<2048,  256, 0, stream>>>(hidden, hchain, allvis);
  k_cvt  <<<16000, 256, 0, stream>>>(who, (uint32_t*)whobf);
  k_xproj<<<1024,  256, 0, stream>>>(ids, table, wxh, bxh, xp);
  k_fused<<<8064,  256, 0, stream>>>(whh, xp, hchain, whobf, whob,
                                     allvis, fin, out, hfinal);
}